// Round 9
// baseline (61.975 us; speedup 1.0000x reference)
//
#include <hip/hip_runtime.h>
#include <hip/hip_bf16.h>

#define B_     4
#define C_     256
#define H_     180
#define W_     180
#define NBOX   64
#define HW_    (H_ * W_)           // 32400
#define GROUPS (HW_ / 4)           // 8100 float4 pixel-groups per channel plane
#define GTILES 32                  // ceil(GROUPS/256)
#define PTILES 127                 // ceil(HW_/256)
#define KCH    16                  // channel chunks
#define CPC    16                  // channels per chunk
#define NBLK   (PTILES * B_)

// workspace layout (bytes)
#define WMASK_OFF 0                                   // u8 [B_][HW_]
#define PSUM_OFF  (B_ * HW_)                          // 129600, 16-aligned; float4 [KCH][B_][GROUPS]
#define PNZ_OFF   (PSUM_OFF + KCH * B_ * GROUPS * 16) // u32 [KCH][B_][GROUPS]
#define ACC_OFF   (PNZ_OFF + KCH * B_ * GROUPS * 4)   // float sum + u32 cnt
#define WS_NEED   (ACC_OFF + 8)                       // 10,497,608 B

// ---------- K1: per-pixel box mask ----------
__global__ __launch_bounds__(256) void mfl_mask(
    const int* __restrict__ boxes,
    unsigned char* __restrict__ wmask)
{
    const int tid = threadIdx.x;
    const int bx  = blockIdx.x;
    const int b   = blockIdx.y;

    __shared__ int sbox[NBOX * 4];
    sbox[tid] = boxes[b * NBOX * 4 + tid];
    __syncthreads();

    const int hw = bx * 256 + tid;
    if (hw < HW_) {
        const int h = hw / W_, w = hw - (hw / W_) * W_;
        int msk = 0;
        #pragma unroll 8
        for (int n = 0; n < NBOX; ++n) {
            const int ltx = sbox[n * 4 + 0];
            const int lty = sbox[n * 4 + 1];
            const int rbx = sbox[n * 4 + 2];
            const int rby = sbox[n * 4 + 3];
            msk |= ((h >= lty) & (h < rby) & (w >= rbx) & (w < ltx));
        }
        wmask[b * HW_ + hw] = (unsigned char)msk;
    }
}

// ---------- K2 (hot): copy-probe-shaped streaming partials ----------
// Grid (GTILES, KCH, B_) = 2048 blocks, 256 thr, launch_bounds(256,8) -> VGPR<=64,
// 32 waves/CU. Thread owns 4 px (one float4 group) x 16 channels entirely in
// registers: 32 float4 loads (1KB/wave each), no LDS, no atomics, no cross-
// thread traffic. Groups with no masked pixel skip everything (fetch gating).
__global__ __launch_bounds__(256, 8) void mfl_stream(
    const float4* __restrict__ x4,
    const float4* __restrict__ t4,
    const unsigned char* __restrict__ wmask,
    float4* __restrict__ psum,
    unsigned int* __restrict__ pnz)
{
    const int g = blockIdx.x * 256 + threadIdx.x;   // float4-group
    if (g >= GROUPS) return;
    const int k = blockIdx.y;
    const int b = blockIdx.z;

    const uchar4 m4 = *(const uchar4*)(wmask + b * HW_ + 4 * g);
    if ((m4.x | m4.y | m4.z | m4.w) == 0) return;   // no masked px in group

    const size_t fbase = ((size_t)(b * C_ + k * CPC)) * GROUPS + g;
    const float4* xp = x4 + fbase;
    const float4* tp = t4 + fbase;

    float a0 = 0.f, a1 = 0.f, a2 = 0.f, a3 = 0.f;
    int   n0 = 0, n1 = 0, n2 = 0, n3 = 0;

    #pragma unroll 4
    for (int c = 0; c < CPC; ++c) {
        const float4 tv = tp[(size_t)c * GROUPS];
        const float4 xv = xp[(size_t)c * GROUPS];
        n0 |= (tv.x != 0.f); n1 |= (tv.y != 0.f);
        n2 |= (tv.z != 0.f); n3 |= (tv.w != 0.f);
        float d0 = xv.x - tv.x, d1 = xv.y - tv.y;
        float d2 = xv.z - tv.z, d3 = xv.w - tv.w;
        float s0 = 0.5f * d0 * d0, s1 = 0.5f * d1 * d1;
        float s2 = 0.5f * d2 * d2, s3 = 0.5f * d3 * d3;
        if (isnan(tv.x)) s0 = 0.f;  if (isnan(tv.y)) s1 = 0.f;
        if (isnan(tv.z)) s2 = 0.f;  if (isnan(tv.w)) s3 = 0.f;
        a0 += s0; a1 += s1; a2 += s2; a3 += s3;
    }

    const size_t o = ((size_t)(k * B_ + b)) * GROUPS + g;
    psum[o] = make_float4(a0, a1, a2, a3);
    pnz[o]  = (unsigned int)n0 | ((unsigned int)n1 << 8)
            | ((unsigned int)n2 << 16) | ((unsigned int)n3 << 24);
}

// ---------- K3: gate by mask & anynz, reduce, 2 atomics/block ----------
__global__ __launch_bounds__(256) void mfl_gate(
    const float* __restrict__ psumf,          // flat float view of psum
    const unsigned char* __restrict__ pnzb,   // flat byte view of pnz
    const unsigned char* __restrict__ wmask,
    float* __restrict__ ws_sum,
    unsigned int* __restrict__ ws_cnt)
{
    const int tid = threadIdx.x;
    const int bx  = blockIdx.x;
    const int b   = blockIdx.y;
    const int hw  = bx * 256 + tid;

    float s = 0.f;
    int   nz = 0, msk = 0;
    if (hw < HW_) {
        msk = wmask[b * HW_ + hw];
        if (msk) {
            const int g = hw >> 2, e = hw & 3;
            #pragma unroll
            for (int k = 0; k < KCH; ++k) {
                const size_t o = ((size_t)(k * B_ + b)) * GROUPS + g;
                s  += psumf[o * 4 + e];
                nz |= pnzb[o * 4 + e];
            }
        }
    }
    const bool ok = msk && nz;
    float sc = ok ? s : 0.f;
    int   cc = ok ? 1 : 0;

    #pragma unroll
    for (int off = 32; off > 0; off >>= 1) {
        sc += __shfl_down(sc, off, 64);
        cc += __shfl_down(cc, off, 64);
    }
    __shared__ float ws[4];
    __shared__ int   wc[4];
    if ((tid & 63) == 0) { ws[tid >> 6] = sc; wc[tid >> 6] = cc; }
    __syncthreads();
    if (tid == 0) {
        const float S  = ws[0] + ws[1] + ws[2] + ws[3];
        const int   Cn = wc[0] + wc[1] + wc[2] + wc[3];
        if (S != 0.f) atomicAdd(ws_sum, S);
        if (Cn != 0)  atomicAdd(ws_cnt, (unsigned int)Cn);
    }
}

__global__ void mfl_final(const float* ws_sum, const unsigned int* ws_cnt,
                          float* out)
{
    out[0] = ws_sum[0] / ((float)ws_cnt[0] * (float)C_ * (float)B_);
}

// ---------- Fallback (ws too small): round-4 fused kernel ----------
__global__ __launch_bounds__(256) void mfl_fallback(
    const float* __restrict__ x, const float* __restrict__ t,
    const int* __restrict__ boxes, float* ws_sum, unsigned int* ws_cnt)
{
    const int p = blockIdx.x * blockDim.x + threadIdx.x;
    float s = 0.0f; int cnt = 0;
    if (p < B_ * HW_) {
        const int b = p / HW_, hw = p - b * HW_;
        const int h = hw / W_, w = hw - h * W_;
        bool mask = false;
        const int* bb = boxes + b * NBOX * 4;
        for (int n = 0; n < NBOX; ++n) {
            mask |= ((h >= bb[n*4+1]) & (h < bb[n*4+3]) & (w >= bb[n*4+2]) & (w < bb[n*4+0]));
        }
        if (mask) {
            const float* xp = x + (size_t)b * C_ * HW_ + hw;
            const float* tp = t + (size_t)b * C_ * HW_ + hw;
            bool anynz = false;
            for (int c = 0; c < C_; ++c) {
                const float tv = tp[(size_t)c * HW_], xv = xp[(size_t)c * HW_];
                anynz |= (tv != 0.0f);
                const float d = xv - tv;
                float term = 0.5f * d * d;
                if (isnan(tv)) term = 0.0f;
                s += term;
            }
            if (anynz) cnt = 1; else s = 0.0f;
        }
    }
    for (int off = 32; off > 0; off >>= 1) {
        s += __shfl_down(s, off, 64); cnt += __shfl_down(cnt, off, 64);
    }
    __shared__ float ssum[4]; __shared__ int scnt[4];
    if ((threadIdx.x & 63) == 0) { ssum[threadIdx.x >> 6] = s; scnt[threadIdx.x >> 6] = cnt; }
    __syncthreads();
    if (threadIdx.x == 0) {
        const float S = ssum[0]+ssum[1]+ssum[2]+ssum[3];
        const int Cn = scnt[0]+scnt[1]+scnt[2]+scnt[3];
        if (S != 0.0f) atomicAdd(ws_sum, S);
        if (Cn != 0) atomicAdd(ws_cnt, (unsigned int)Cn);
    }
}

extern "C" void kernel_launch(void* const* d_in, const int* in_sizes, int n_in,
                              void* d_out, int out_size, void* d_ws, size_t ws_size,
                              hipStream_t stream)
{
    const float* x     = (const float*)d_in[0];
    const float* t     = (const float*)d_in[1];
    const int*   boxes = (const int*)d_in[2];
    float* out = (float*)d_out;
    char*  ws  = (char*)d_ws;

    if (ws_size < (size_t)WS_NEED) {
        float* ws_sum = (float*)ws;
        unsigned int* ws_cnt = (unsigned int*)(ws + 4);
        hipMemsetAsync(d_ws, 0, 8, stream);
        mfl_fallback<<<(B_ * HW_ + 255) / 256, 256, 0, stream>>>(x, t, boxes, ws_sum, ws_cnt);
        mfl_final<<<1, 1, 0, stream>>>(ws_sum, ws_cnt, out);
        return;
    }

    unsigned char* wmask  = (unsigned char*)(ws + WMASK_OFF);
    float4*        psum   = (float4*)(ws + PSUM_OFF);
    unsigned int*  pnz    = (unsigned int*)(ws + PNZ_OFF);
    float*         ws_sum = (float*)(ws + ACC_OFF);
    unsigned int*  ws_cnt = (unsigned int*)(ws + ACC_OFF + 4);

    hipMemsetAsync(ws + ACC_OFF, 0, 8, stream);

    dim3 gm(PTILES, B_);
    mfl_mask<<<gm, 256, 0, stream>>>(boxes, wmask);

    dim3 ga(GTILES, KCH, B_);
    mfl_stream<<<ga, 256, 0, stream>>>((const float4*)x, (const float4*)t,
                                       wmask, psum, pnz);

    dim3 gb(PTILES, B_);
    mfl_gate<<<gb, 256, 0, stream>>>((const float*)psum,
                                     (const unsigned char*)pnz,
                                     wmask, ws_sum, ws_cnt);

    mfl_final<<<1, 1, 0, stream>>>(ws_sum, ws_cnt, out);
}